// Round 1
// baseline (9148.701 us; speedup 1.0000x reference)
//
#include <hip/hip_runtime.h>
#include <cstddef>

#define THRESH 0.1f

constexpr int Bn = 8, C = 256, H = 128, W = 128;
constexpr int HW = H * W;
constexpr size_t CHW = (size_t)C * HW;
constexpr size_t NELEM = (size_t)Bn * CHW;

// masked prelu: t = prelu(v); return |t| >= THRESH ? t : 0
__device__ __forceinline__ float pm(float v, float a) {
    float t = (v >= 0.f) ? v : a * v;
    return (fabsf(t) >= THRESH) ? t : 0.f;
}

// Direct 3x3 conv, stride 1, pad 1, fp32. Applies pm() to inputs at LDS-stage
// time. Block: 256 threads = 128 w-cols x 2 row-quads. Each thread computes
// 8 output channels x 2 output rows. Block tile: 8 co x 4 h x 128 w.
// grid = (C/8, H/4, Bn)
__global__ __launch_bounds__(256, 4) void conv_pm_kernel(
    const float* __restrict__ in, const float* __restrict__ wgt,
    const float* __restrict__ bias, const float* __restrict__ pa,
    float* __restrict__ out)
{
    __shared__ float s[6 * 132];   // rows h0-1..h0+4, cols -1..130 (halo), stride 132
    const int tid = threadIdx.x;
    const int w   = tid & 127;
    const int hq  = tid >> 7;          // 0 or 1
    const int co0 = blockIdx.x * 8;
    const int h0  = blockIdx.y * 4;
    const int b   = blockIdx.z;
    const float a = pa[0];

    float acc[2][8];
#pragma unroll
    for (int j = 0; j < 8; ++j) {
        float bj = bias[co0 + j];
        acc[0][j] = bj; acc[1][j] = bj;
    }

    const float* inb = in + (size_t)b * CHW;

    for (int ci = 0; ci < C; ++ci) {
        __syncthreads();   // previous iteration's LDS reads done
        const float* src = inb + (size_t)ci * HW;
        for (int idx = tid; idx < 6 * 132; idx += 256) {
            int r = idx / 132, c = idx - r * 132;
            int hh = h0 - 1 + r;     // input row
            int ww = c - 1;          // input col
            float v = 0.f;
            if ((unsigned)hh < (unsigned)H && (unsigned)ww < (unsigned)W)
                v = pm(src[hh * W + ww], a);
            s[idx] = v;
        }
        __syncthreads();

        // each thread's 4x3 activation window (stride-1 per wave: conflict-free)
        float acts[4][3];
#pragma unroll
        for (int r = 0; r < 4; ++r)
#pragma unroll
            for (int c = 0; c < 3; ++c)
                acts[r][c] = s[(2 * hq + r) * 132 + w + c];

        // weights are block-uniform -> scalar loads
#pragma unroll
        for (int j = 0; j < 8; ++j) {
            const float* wp = wgt + ((size_t)(co0 + j) * C + ci) * 9;
#pragma unroll
            for (int ky = 0; ky < 3; ++ky) {
#pragma unroll
                for (int kx = 0; kx < 3; ++kx) {
                    float wv = wp[ky * 3 + kx];
                    acc[0][j] = fmaf(wv, acts[ky][kx],     acc[0][j]);
                    acc[1][j] = fmaf(wv, acts[ky + 1][kx], acc[1][j]);
                }
            }
        }
    }

#pragma unroll
    for (int rr = 0; rr < 2; ++rr) {
        int hh = h0 + 2 * hq + rr;
#pragma unroll
        for (int j = 0; j < 8; ++j)
            out[((size_t)b * C + co0 + j) * HW + hh * W + w] = acc[rr][j];
    }
}

__global__ void ew_max_kernel(const float4* __restrict__ a,
                              const float4* __restrict__ b,
                              float4* __restrict__ d, int n4)
{
    int i = blockIdx.x * blockDim.x + threadIdx.x;
    int stride = gridDim.x * blockDim.x;
    for (; i < n4; i += stride) {
        float4 x = a[i], y = b[i];
        float4 r;
        r.x = fmaxf(x.x, y.x); r.y = fmaxf(x.y, y.y);
        r.z = fmaxf(x.z, y.z); r.w = fmaxf(x.w, y.w);
        d[i] = r;
    }
}

extern "C" void kernel_launch(void* const* d_in, const int* in_sizes, int n_in,
                              void* d_out, int out_size, void* d_ws, size_t ws_size,
                              hipStream_t stream)
{
    const float* x  = (const float*)d_in[0];
    const float* w1 = (const float*)d_in[1];
    const float* b1 = (const float*)d_in[2];
    const float* w2 = (const float*)d_in[3];
    const float* b2 = (const float*)d_in[4];
    const float* w3 = (const float*)d_in[5];
    const float* b3 = (const float*)d_in[6];
    const float* pa = (const float*)d_in[7];
    float* out = (float*)d_out;

    float* buf0 = (float*)d_ws;          // 134 MB
    float* buf1 = buf0 + NELEM;          // 134 MB

    dim3 grid(C / 8, H / 4, Bn);
    dim3 block(256);
    const int n4 = (int)(NELEM / 4);
    dim3 egrid(2048), eblock(256);

    // 1. buf0 = conv_pm(x; w1,b1)                  (= x0)
    conv_pm_kernel<<<grid, block, 0, stream>>>(x, w1, b1, pa, buf0);
    // 2. buf1 = max(x, buf0)                       (= x1_max)
    ew_max_kernel<<<egrid, eblock, 0, stream>>>((const float4*)x, (const float4*)buf0,
                                                (float4*)buf1, n4);
    // 3. buf0 = conv_pm(buf1; w2,b2)               (= x1c)
    conv_pm_kernel<<<grid, block, 0, stream>>>(buf1, w2, b2, pa, buf0);
    // 4. buf1 = max(buf0, buf1)                    (= x2_max)
    ew_max_kernel<<<egrid, eblock, 0, stream>>>((const float4*)buf0, (const float4*)buf1,
                                                (float4*)buf1, n4);
    // 5. out = conv_pm(buf1; w3,b3)
    conv_pm_kernel<<<grid, block, 0, stream>>>(buf1, w3, b3, pa, out);
}

// Round 3
// 1422.685 us; speedup vs baseline: 6.4306x; 6.4306x over previous
//
#include <hip/hip_runtime.h>
#include <cstddef>

#define THRESH 0.1f

constexpr int Bn = 8, C = 256, H = 128, W = 128;
constexpr int HW = H * W;
constexpr size_t CHW = (size_t)C * HW;
constexpr size_t NELEM = (size_t)Bn * CHW;
constexpr int WSZ = 9 * 256 * 256;          // elements per transformed weight

typedef __attribute__((ext_vector_type(8))) short short8;   // 8 bf16
typedef __attribute__((ext_vector_type(4))) float f32x4;

__device__ __forceinline__ float bf2f(ushort u) {
    union { unsigned u; float f; } v; v.u = ((unsigned)u) << 16; return v.f;
}
__device__ __forceinline__ ushort f2bf(float f) {
    union { float f; unsigned u; } v; v.f = f;
    unsigned r = v.u + 0x7FFF + ((v.u >> 16) & 1);   // RNE
    return (ushort)(r >> 16);
}
__device__ __forceinline__ float pm(float x, float a) {
    float t = (x >= 0.f) ? x : a * x;                 // prelu
    return (fabsf(t) >= THRESH) ? t : 0.f;            // NaNConv input mask
}

// ---------------------------------------------------------------------------
// Weight transform: fp32 [co][ci][3][3] -> bf16 fragment-major
// [co>>6][ci>>5][tap][mfrag][lane64][8]   (lane = (co&15) + 16*((ci>>3)&3))
// so conv's LDS staging AND A-fragment reads are fully contiguous.
__global__ void wtrans_kernel(const float* __restrict__ w1,
                              const float* __restrict__ w2,
                              const float* __restrict__ w3,
                              ushort* __restrict__ Wtf)
{
    const float* src = (blockIdx.z == 0) ? w1 : (blockIdx.z == 1) ? w2 : w3;
    ushort* dst = Wtf + (size_t)blockIdx.z * WSZ;
    int idx = blockIdx.x * 256 + threadIdx.x;   // 0..65535 = co*256+ci
    int co = idx >> 8, ci = idx & 255;
    int cb  = co >> 6;
    int m   = (co >> 4) & 3;
    int l15 = co & 15;
    int cib = ci >> 5;
    int l4  = (ci >> 3) & 3;
    int j   = ci & 7;
    int lane = l15 + 16 * l4;
    for (int t = 0; t < 9; ++t) {
        float v = src[((size_t)co * 256 + ci) * 9 + t];
        size_t o = ((((size_t)cb * 8 + cib) * 9 + t) * 4 + m) * 512 + lane * 8 + j;
        dst[o] = f2bf(v);
    }
}

// ---------------------------------------------------------------------------
// x (fp32 NCHW) -> Xt (bf16 NHWC) with pm applied.  grid (4, 128, 8)
__global__ __launch_bounds__(256) void xt1_kernel(const float* __restrict__ x,
                                                  const float* __restrict__ pa,
                                                  ushort* __restrict__ Xt)
{
    __shared__ float sl[64][133];
    int tid = threadIdx.x;
    int ci0 = blockIdx.x * 64, h = blockIdx.y, b = blockIdx.z;
    float a = pa[0];
    int wcol = tid & 127, chalf = tid >> 7;
    const float* xb = x + (size_t)b * CHW + (size_t)ci0 * HW + h * W;
    for (int r = 0; r < 32; ++r) {
        int ci = r * 2 + chalf;
        sl[ci][wcol] = pm(xb[(size_t)ci * HW + wcol], a);
    }
    __syncthreads();
    ushort* dst = Xt + ((size_t)(b * H + h)) * W * C + ci0;
    for (int r = 0; r < 4; ++r) {
        int c = r * 256 + tid;
        int wc = c >> 3, cic = c & 7;
        unsigned p0 = f2bf(sl[cic*8+0][wc]) | ((unsigned)f2bf(sl[cic*8+1][wc]) << 16);
        unsigned p1 = f2bf(sl[cic*8+2][wc]) | ((unsigned)f2bf(sl[cic*8+3][wc]) << 16);
        unsigned p2 = f2bf(sl[cic*8+4][wc]) | ((unsigned)f2bf(sl[cic*8+5][wc]) << 16);
        unsigned p3 = f2bf(sl[cic*8+6][wc]) | ((unsigned)f2bf(sl[cic*8+7][wc]) << 16);
        uint4 v = {p0, p1, p2, p3};
        *(uint4*)(dst + (size_t)wc * C + cic * 8) = v;
    }
}

// x (fp32 NCHW) + y (bf16 NCHW) -> xmax=max(x,y) (bf16 NCHW), Xt=pm(max) (bf16 NHWC)
__global__ __launch_bounds__(256) void maxt1_kernel(const float* __restrict__ x,
                                                    const ushort* __restrict__ y,
                                                    const float* __restrict__ pa,
                                                    ushort* __restrict__ xmax,
                                                    ushort* __restrict__ Xt)
{
    __shared__ float sl[64][133];
    int tid = threadIdx.x;
    int ci0 = blockIdx.x * 64, h = blockIdx.y, b = blockIdx.z;
    float a = pa[0];
    int wcol = tid & 127, chalf = tid >> 7;
    for (int r = 0; r < 32; ++r) {
        int ci = r * 2 + chalf;
        size_t gi = (size_t)b * CHW + (size_t)(ci0 + ci) * HW + h * W + wcol;
        float m = fmaxf(x[gi], bf2f(y[gi]));
        xmax[gi] = f2bf(m);
        sl[ci][wcol] = pm(m, a);
    }
    __syncthreads();
    ushort* dst = Xt + ((size_t)(b * H + h)) * W * C + ci0;
    for (int r = 0; r < 4; ++r) {
        int c = r * 256 + tid;
        int wc = c >> 3, cic = c & 7;
        unsigned p0 = f2bf(sl[cic*8+0][wc]) | ((unsigned)f2bf(sl[cic*8+1][wc]) << 16);
        unsigned p1 = f2bf(sl[cic*8+2][wc]) | ((unsigned)f2bf(sl[cic*8+3][wc]) << 16);
        unsigned p2 = f2bf(sl[cic*8+4][wc]) | ((unsigned)f2bf(sl[cic*8+5][wc]) << 16);
        unsigned p3 = f2bf(sl[cic*8+6][wc]) | ((unsigned)f2bf(sl[cic*8+7][wc]) << 16);
        uint4 v = {p0, p1, p2, p3};
        *(uint4*)(dst + (size_t)wc * C + cic * 8) = v;
    }
}

// y (bf16 NCHW) + xm (bf16 NCHW) -> Xt = pm(max(y,xm)) (bf16 NHWC)
__global__ __launch_bounds__(256) void maxt2_kernel(const ushort* __restrict__ y,
                                                    const ushort* __restrict__ xm,
                                                    const float* __restrict__ pa,
                                                    ushort* __restrict__ Xt)
{
    __shared__ float sl[64][133];
    int tid = threadIdx.x;
    int ci0 = blockIdx.x * 64, h = blockIdx.y, b = blockIdx.z;
    float a = pa[0];
    int wcol = tid & 127, chalf = tid >> 7;
    for (int r = 0; r < 32; ++r) {
        int ci = r * 2 + chalf;
        size_t gi = (size_t)b * CHW + (size_t)(ci0 + ci) * HW + h * W + wcol;
        float m = fmaxf(bf2f(y[gi]), bf2f(xm[gi]));
        sl[ci][wcol] = pm(m, a);
    }
    __syncthreads();
    ushort* dst = Xt + ((size_t)(b * H + h)) * W * C + ci0;
    for (int r = 0; r < 4; ++r) {
        int c = r * 256 + tid;
        int wc = c >> 3, cic = c & 7;
        unsigned p0 = f2bf(sl[cic*8+0][wc]) | ((unsigned)f2bf(sl[cic*8+1][wc]) << 16);
        unsigned p1 = f2bf(sl[cic*8+2][wc]) | ((unsigned)f2bf(sl[cic*8+3][wc]) << 16);
        unsigned p2 = f2bf(sl[cic*8+4][wc]) | ((unsigned)f2bf(sl[cic*8+5][wc]) << 16);
        unsigned p3 = f2bf(sl[cic*8+6][wc]) | ((unsigned)f2bf(sl[cic*8+7][wc]) << 16);
        uint4 v = {p0, p1, p2, p3};
        *(uint4*)(dst + (size_t)wc * C + cic * 8) = v;
    }
}

// ---------------------------------------------------------------------------
// Implicit-GEMM 3x3 conv, bf16 MFMA. Block: 64 co x 128 w (one (b,h) row),
// 4 waves, wave = 4 mfrag x 2 nfrag of 16x16x32 MFMA. grid (4, 1024).
__device__ __forceinline__ void stv(float* p, float v)  { *p = v; }
__device__ __forceinline__ void stv(ushort* p, float v) { *p = f2bf(v); }

template <typename OT>
__global__ __launch_bounds__(256, 2) void conv_kernel(
    const ushort* __restrict__ Xt, const ushort* __restrict__ Wtf,
    const float* __restrict__ bias, OT* __restrict__ out)
{
    // sa: [ky3][cic4][wi132][8ci]  (wi = w'+1, halo)  = 25344 B
    // sw: [tap9][mfrag4][lane64][8ci] per ci-block     = 36864 B
    __shared__ __align__(16) ushort sa[3 * 4 * 132 * 8];
    __shared__ __align__(16) ushort sw[9 * 4 * 64 * 8];

    const int tid = threadIdx.x, lane = tid & 63, wv = tid >> 6;
    const int cb = blockIdx.x;           // co0 = cb*64
    const int co0 = cb * 64;
    const int bh = blockIdx.y;
    const int b = bh >> 7, h = bh & 127;
    const int l15 = lane & 15, l4 = lane >> 4;

    f32x4 acc[4][2];
    const f32x4 z4 = {0.f, 0.f, 0.f, 0.f};
#pragma unroll
    for (int m = 0; m < 4; ++m)
#pragma unroll
        for (int n = 0; n < 2; ++n) acc[m][n] = z4;

    const ushort* xb = Xt + (size_t)b * H * W * C;

    for (int cib = 0; cib < 8; ++cib) {
        const int ci0 = cib * 32;
        __syncthreads();
        // stage weights: contiguous copy of this (cb,cib) slice
        // 18432 ushorts = 2304 uint4   (round-2 bug: was 1152 = half the tile)
        {
            const uint4* src = (const uint4*)(Wtf + (((size_t)cb * 8 + cib) * 18432));
            uint4* dst = (uint4*)sw;
            for (int i = tid; i < 2304; i += 256) dst[i] = src[i];
        }
        // stage activations: [ky][cic][wi] chunks of 8 ci (1584 x 16B)
        for (int i = tid; i < 1584; i += 256) {
            int wi = i % 132;
            int rem = i / 132;
            int cic = rem & 3, ky = rem >> 2;
            int hh = h - 1 + ky, ww = wi - 1;
            uint4 v = {0, 0, 0, 0};
            if ((unsigned)hh < 128u && (unsigned)ww < 128u)
                v = *(const uint4*)(xb + ((size_t)hh * W + ww) * C + ci0 + cic * 8);
            *(uint4*)(sa + (((ky * 4 + cic) * 132) + wi) * 8) = v;
        }
        __syncthreads();

#pragma unroll
        for (int t = 0; t < 9; ++t) {
            const int ky = t / 3, kx = t % 3;
            short8 af[4], bfv[2];
#pragma unroll
            for (int m = 0; m < 4; ++m)
                af[m] = *(const short8*)(sw + (((t * 4 + m) * 64) + lane) * 8);
#pragma unroll
            for (int n = 0; n < 2; ++n) {
                int wi = wv * 32 + n * 16 + l15 + kx;   // w' + 1
                bfv[n] = *(const short8*)(sa + (((ky * 4 + l4) * 132) + wi) * 8);
            }
#pragma unroll
            for (int m = 0; m < 4; ++m)
#pragma unroll
                for (int n = 0; n < 2; ++n)
                    acc[m][n] = __builtin_amdgcn_mfma_f32_16x16x32_bf16(
                        af[m], bfv[n], acc[m][n], 0, 0, 0);
        }
    }

    // epilogue: D row = l4*4+r (co), col = l15 (w)
#pragma unroll
    for (int m = 0; m < 4; ++m)
#pragma unroll
        for (int n = 0; n < 2; ++n)
#pragma unroll
            for (int r = 0; r < 4; ++r) {
                int co = co0 + m * 16 + l4 * 4 + r;
                int wc = wv * 32 + n * 16 + l15;
                float v = acc[m][n][r] + bias[co];
                stv(out + ((size_t)(b * C + co) * H + h) * W + wc, v);
            }
}

// ---------------------------------------------------------------------------
extern "C" void kernel_launch(void* const* d_in, const int* in_sizes, int n_in,
                              void* d_out, int out_size, void* d_ws, size_t ws_size,
                              hipStream_t stream)
{
    const float* x  = (const float*)d_in[0];
    const float* w1 = (const float*)d_in[1];
    const float* b1 = (const float*)d_in[2];
    const float* w2 = (const float*)d_in[3];
    const float* b2 = (const float*)d_in[4];
    const float* w3 = (const float*)d_in[5];
    const float* b3 = (const float*)d_in[6];
    const float* pa = (const float*)d_in[7];

    char* ws = (char*)d_ws;
    ushort* Xt   = (ushort*)ws;                       // 67108864 B (bf16 NHWC)
    ushort* ybuf = (ushort*)(ws + 67108864);          // 67108864 B (bf16 NCHW)
    ushort* xmax = (ushort*)(ws + 134217728);         // 67108864 B (bf16 NCHW)
    ushort* Wtf  = (ushort*)(ws + 201326592);         // 3 x 1179648 B

    dim3 tg(4, 128, 8), tb(256);
    dim3 cg(4, 1024), cbk(256);

    wtrans_kernel<<<dim3(256, 1, 3), 256, 0, stream>>>(w1, w2, w3, Wtf);
    // conv1: Xt = pm(x);  ybuf = conv(Xt, w1) + b1
    xt1_kernel<<<tg, tb, 0, stream>>>(x, pa, Xt);
    conv_kernel<ushort><<<cg, cbk, 0, stream>>>(Xt, Wtf, b1, ybuf);
    // x1_max = max(x, ybuf) -> xmax;  Xt = pm(x1_max)
    maxt1_kernel<<<tg, tb, 0, stream>>>(x, ybuf, pa, xmax, Xt);
    // conv2: ybuf = conv(Xt, w2) + b2
    conv_kernel<ushort><<<cg, cbk, 0, stream>>>(Xt, Wtf + WSZ, b2, ybuf);
    // x2_max = max(ybuf, xmax);  Xt = pm(x2_max)
    maxt2_kernel<<<tg, tb, 0, stream>>>(ybuf, xmax, pa, Xt);
    // conv3 -> fp32 out
    conv_kernel<float><<<cg, cbk, 0, stream>>>(Xt, Wtf + 2 * WSZ, b3, (float*)d_out);
}

// Round 4
// 862.192 us; speedup vs baseline: 10.6110x; 1.6501x over previous
//
#include <hip/hip_runtime.h>
#include <cstddef>

#define THRESH 0.1f

constexpr int Bn = 8, C = 256, H = 128, W = 128;
constexpr int HW = H * W;
constexpr size_t CHW = (size_t)C * HW;
constexpr size_t NELEM = (size_t)Bn * CHW;
constexpr int WSZ = 9 * 256 * 256;          // elements per transformed weight

typedef __attribute__((ext_vector_type(8))) short short8;   // 8 bf16
typedef __attribute__((ext_vector_type(4))) float f32x4;

__device__ __forceinline__ float bf2f(ushort u) {
    union { unsigned u; float f; } v; v.u = ((unsigned)u) << 16; return v.f;
}
__device__ __forceinline__ ushort f2bf(float f) {
    union { float f; unsigned u; } v; v.f = f;
    unsigned r = v.u + 0x7FFF + ((v.u >> 16) & 1);   // RNE
    return (ushort)(r >> 16);
}
__device__ __forceinline__ float pm(float x, float a) {
    float t = (x >= 0.f) ? x : a * x;                 // prelu
    return (fabsf(t) >= THRESH) ? t : 0.f;            // NaNConv input mask
}

// async global->LDS, 16 B per lane; LDS side is wave-uniform base + lane*16
__device__ __forceinline__ void load_lds16(const void* g, void* l) {
    __builtin_amdgcn_global_load_lds(
        (const __attribute__((address_space(1))) unsigned int*)g,
        (__attribute__((address_space(3))) unsigned int*)l, 16, 0, 0);
}

// ---------------------------------------------------------------------------
// Weight transform: fp32 [co][ci][3][3] -> bf16 fragment-major
// [co>>6][ci>>5][tap][mfrag][lane64][8]   (lane = (co&15) + 16*((ci>>3)&3))
__global__ void wtrans_kernel(const float* __restrict__ w1,
                              const float* __restrict__ w2,
                              const float* __restrict__ w3,
                              ushort* __restrict__ Wtf)
{
    const float* src = (blockIdx.z == 0) ? w1 : (blockIdx.z == 1) ? w2 : w3;
    ushort* dst = Wtf + (size_t)blockIdx.z * WSZ;
    int idx = blockIdx.x * 256 + threadIdx.x;   // 0..65535 = co*256+ci
    int co = idx >> 8, ci = idx & 255;
    int cb  = co >> 6;
    int m   = (co >> 4) & 3;
    int l15 = co & 15;
    int cib = ci >> 5;
    int l4  = (ci >> 3) & 3;
    int j   = ci & 7;
    int lane = l15 + 16 * l4;
    for (int t = 0; t < 9; ++t) {
        float v = src[((size_t)co * 256 + ci) * 9 + t];
        size_t o = ((((size_t)cb * 8 + cib) * 9 + t) * 4 + m) * 512 + lane * 8 + j;
        dst[o] = f2bf(v);
    }
}

// ---------------------------------------------------------------------------
// x (fp32 NCHW) -> Xt (bf16 NHWC) with pm applied.  grid (4, 128, 8)
__global__ __launch_bounds__(256) void xt1_kernel(const float* __restrict__ x,
                                                  const float* __restrict__ pa,
                                                  ushort* __restrict__ Xt)
{
    __shared__ float sl[64][133];
    int tid = threadIdx.x;
    int ci0 = blockIdx.x * 64, h = blockIdx.y, b = blockIdx.z;
    float a = pa[0];
    int wcol = tid & 127, chalf = tid >> 7;
    const float* xb = x + (size_t)b * CHW + (size_t)ci0 * HW + h * W;
    for (int r = 0; r < 32; ++r) {
        int ci = r * 2 + chalf;
        sl[ci][wcol] = pm(xb[(size_t)ci * HW + wcol], a);
    }
    __syncthreads();
    ushort* dst = Xt + ((size_t)(b * H + h)) * W * C + ci0;
    for (int r = 0; r < 4; ++r) {
        int c = r * 256 + tid;
        int wc = c >> 3, cic = c & 7;
        unsigned p0 = f2bf(sl[cic*8+0][wc]) | ((unsigned)f2bf(sl[cic*8+1][wc]) << 16);
        unsigned p1 = f2bf(sl[cic*8+2][wc]) | ((unsigned)f2bf(sl[cic*8+3][wc]) << 16);
        unsigned p2 = f2bf(sl[cic*8+4][wc]) | ((unsigned)f2bf(sl[cic*8+5][wc]) << 16);
        unsigned p3 = f2bf(sl[cic*8+6][wc]) | ((unsigned)f2bf(sl[cic*8+7][wc]) << 16);
        uint4 v = {p0, p1, p2, p3};
        *(uint4*)(dst + (size_t)wc * C + cic * 8) = v;
    }
}

// x (fp32 NCHW) + y (bf16 NCHW) -> xmax=max(x,y) (bf16 NCHW), Xt=pm(max) (bf16 NHWC)
__global__ __launch_bounds__(256) void maxt1_kernel(const float* __restrict__ x,
                                                    const ushort* __restrict__ y,
                                                    const float* __restrict__ pa,
                                                    ushort* __restrict__ xmax,
                                                    ushort* __restrict__ Xt)
{
    __shared__ float sl[64][133];
    int tid = threadIdx.x;
    int ci0 = blockIdx.x * 64, h = blockIdx.y, b = blockIdx.z;
    float a = pa[0];
    int wcol = tid & 127, chalf = tid >> 7;
    for (int r = 0; r < 32; ++r) {
        int ci = r * 2 + chalf;
        size_t gi = (size_t)b * CHW + (size_t)(ci0 + ci) * HW + h * W + wcol;
        float m = fmaxf(x[gi], bf2f(y[gi]));
        xmax[gi] = f2bf(m);
        sl[ci][wcol] = pm(m, a);
    }
    __syncthreads();
    ushort* dst = Xt + ((size_t)(b * H + h)) * W * C + ci0;
    for (int r = 0; r < 4; ++r) {
        int c = r * 256 + tid;
        int wc = c >> 3, cic = c & 7;
        unsigned p0 = f2bf(sl[cic*8+0][wc]) | ((unsigned)f2bf(sl[cic*8+1][wc]) << 16);
        unsigned p1 = f2bf(sl[cic*8+2][wc]) | ((unsigned)f2bf(sl[cic*8+3][wc]) << 16);
        unsigned p2 = f2bf(sl[cic*8+4][wc]) | ((unsigned)f2bf(sl[cic*8+5][wc]) << 16);
        unsigned p3 = f2bf(sl[cic*8+6][wc]) | ((unsigned)f2bf(sl[cic*8+7][wc]) << 16);
        uint4 v = {p0, p1, p2, p3};
        *(uint4*)(dst + (size_t)wc * C + cic * 8) = v;
    }
}

// y (bf16 NCHW) + xm (bf16 NCHW) -> Xt = pm(max(y,xm)) (bf16 NHWC)
__global__ __launch_bounds__(256) void maxt2_kernel(const ushort* __restrict__ y,
                                                    const ushort* __restrict__ xm,
                                                    const float* __restrict__ pa,
                                                    ushort* __restrict__ Xt)
{
    __shared__ float sl[64][133];
    int tid = threadIdx.x;
    int ci0 = blockIdx.x * 64, h = blockIdx.y, b = blockIdx.z;
    float a = pa[0];
    int wcol = tid & 127, chalf = tid >> 7;
    for (int r = 0; r < 32; ++r) {
        int ci = r * 2 + chalf;
        size_t gi = (size_t)b * CHW + (size_t)(ci0 + ci) * HW + h * W + wcol;
        float m = fmaxf(bf2f(y[gi]), bf2f(xm[gi]));
        sl[ci][wcol] = pm(m, a);
    }
    __syncthreads();
    ushort* dst = Xt + ((size_t)(b * H + h)) * W * C + ci0;
    for (int r = 0; r < 4; ++r) {
        int c = r * 256 + tid;
        int wc = c >> 3, cic = c & 7;
        unsigned p0 = f2bf(sl[cic*8+0][wc]) | ((unsigned)f2bf(sl[cic*8+1][wc]) << 16);
        unsigned p1 = f2bf(sl[cic*8+2][wc]) | ((unsigned)f2bf(sl[cic*8+3][wc]) << 16);
        unsigned p2 = f2bf(sl[cic*8+4][wc]) | ((unsigned)f2bf(sl[cic*8+5][wc]) << 16);
        unsigned p3 = f2bf(sl[cic*8+6][wc]) | ((unsigned)f2bf(sl[cic*8+7][wc]) << 16);
        uint4 v = {p0, p1, p2, p3};
        *(uint4*)(dst + (size_t)wc * C + cic * 8) = v;
    }
}

// ---------------------------------------------------------------------------
// Implicit-GEMM 3x3 conv, bf16 MFMA.
// Block: 64 co x (2 h-rows x 128 w) = 64 x 256 GEMM tile, 4 waves.
// Wave: 4 mfrag x 4 nfrag of 16x16x32; wave wv -> hrow = wv>>1, whalf = wv&1.
// Activations: global_load_lds into sa[r4][wi132][ci32]; halo stays zero.
// Weights: A-frags read directly from global (L2-resident, fragment-major).
// grid (4, 512)  [cb, b*64 + hpair]
__device__ __forceinline__ void stv(float* p, float v)  { *p = v; }
__device__ __forceinline__ void stv(ushort* p, float v) { *p = f2bf(v); }

template <typename OT>
__global__ __launch_bounds__(256, 2) void conv_kernel(
    const ushort* __restrict__ Xt, const ushort* __restrict__ Wtf,
    const float* __restrict__ bias, OT* __restrict__ out)
{
    __shared__ __align__(16) ushort sa[4 * 132 * 32];   // 33792 B

    const int tid = threadIdx.x, lane = tid & 63, wv = tid >> 6;
    const int cb = blockIdx.x, co0 = cb * 64;
    const int by = blockIdx.y;
    const int b = by >> 6, h0 = (by & 63) * 2;
    const int l15 = lane & 15, l4 = lane >> 4;
    const int hrow = wv >> 1, whalf = wv & 1;

    // zero whole sa once; OOB rows / halo chunks are never overwritten
    {
        uint4 z = {0, 0, 0, 0};
        uint4* zp = (uint4*)sa;
        for (int i = tid; i < 2112; i += 256) zp[i] = z;
    }

    f32x4 acc[4][4];
    const f32x4 z4 = {0.f, 0.f, 0.f, 0.f};
#pragma unroll
    for (int m = 0; m < 4; ++m)
#pragma unroll
        for (int n = 0; n < 4; ++n) acc[m][n] = z4;

    const ushort* xb = Xt + (size_t)b * H * W * C;
    // this wave stages row sr (hh = h0-1+sr); lane l -> w-chunk seg*16+(l>>2), 16B quarter l&3
    const int sr = wv;
    const int shh = h0 - 1 + sr;
    const bool svalid = (unsigned)shh < 128u;
    const ushort* sgbase = xb + (size_t)shh * W * C;
    ushort* slbase = sa + (sr * 132 + 1) * 32;
    const int lchunk = lane >> 2, lsub = lane & 3;

    for (int cib = 0; cib < 8; ++cib) {
        const int ci0 = cib * 32;
        __syncthreads();                      // prev cib's reads complete
        if (svalid) {
#pragma unroll
            for (int seg = 0; seg < 8; ++seg) {
                int ww = seg * 16 + lchunk;   // 0..127
                const void* gp = sgbase + (size_t)ww * C + ci0 + lsub * 8;
                load_lds16(gp, slbase + seg * 512);   // 512 ushort = 16 chunks
            }
        }
        __syncthreads();                      // staging visible (vmcnt drained)

        const ushort* wB = Wtf + ((size_t)cb * 8 + cib) * 18432;  // 9 taps x 4 m x 512
#pragma unroll
        for (int ky = 0; ky < 3; ++ky) {
            const int r = hrow + ky;
#pragma unroll
            for (int kx = 0; kx < 3; ++kx) {
                const int t = ky * 3 + kx;
                short8 af[4], bfv[4];
#pragma unroll
                for (int m = 0; m < 4; ++m)
                    af[m] = *(const short8*)(wB + (size_t)(t * 4 + m) * 512 + lane * 8);
#pragma unroll
                for (int n = 0; n < 4; ++n) {
                    int wi = whalf * 64 + n * 16 + l15 + kx;      // 0..129
                    bfv[n] = *(const short8*)(sa + ((r * 132 + wi) * 32) + l4 * 8);
                }
#pragma unroll
                for (int m = 0; m < 4; ++m)
#pragma unroll
                    for (int n = 0; n < 4; ++n)
                        acc[m][n] = __builtin_amdgcn_mfma_f32_16x16x32_bf16(
                            af[m], bfv[n], acc[m][n], 0, 0, 0);
            }
        }
    }

    // epilogue: D row = l4*4+rr (co), col = l15 (w)
    const int h = h0 + hrow;
#pragma unroll
    for (int m = 0; m < 4; ++m)
#pragma unroll
        for (int n = 0; n < 4; ++n)
#pragma unroll
            for (int rr = 0; rr < 4; ++rr) {
                int co = co0 + m * 16 + l4 * 4 + rr;
                int wc = whalf * 64 + n * 16 + l15;
                float v = acc[m][n][rr] + bias[co];
                stv(out + ((size_t)(b * C + co) * H + h) * W + wc, v);
            }
}

// ---------------------------------------------------------------------------
extern "C" void kernel_launch(void* const* d_in, const int* in_sizes, int n_in,
                              void* d_out, int out_size, void* d_ws, size_t ws_size,
                              hipStream_t stream)
{
    const float* x  = (const float*)d_in[0];
    const float* w1 = (const float*)d_in[1];
    const float* b1 = (const float*)d_in[2];
    const float* w2 = (const float*)d_in[3];
    const float* b2 = (const float*)d_in[4];
    const float* w3 = (const float*)d_in[5];
    const float* b3 = (const float*)d_in[6];
    const float* pa = (const float*)d_in[7];

    char* ws = (char*)d_ws;
    ushort* Xt   = (ushort*)ws;                       // 67108864 B (bf16 NHWC)
    ushort* ybuf = (ushort*)(ws + 67108864);          // 67108864 B (bf16 NCHW)
    ushort* xmax = (ushort*)(ws + 134217728);         // 67108864 B (bf16 NCHW)
    ushort* Wtf  = (ushort*)(ws + 201326592);         // 3 x 1179648 B

    dim3 tg(4, 128, 8), tb(256);
    dim3 cg(4, 512), cbk(256);

    wtrans_kernel<<<dim3(256, 1, 3), 256, 0, stream>>>(w1, w2, w3, Wtf);
    // conv1: Xt = pm(x);  ybuf = conv(Xt, w1) + b1
    xt1_kernel<<<tg, tb, 0, stream>>>(x, pa, Xt);
    conv_kernel<ushort><<<cg, cbk, 0, stream>>>(Xt, Wtf, b1, ybuf);
    // x1_max = max(x, ybuf) -> xmax;  Xt = pm(x1_max)
    maxt1_kernel<<<tg, tb, 0, stream>>>(x, ybuf, pa, xmax, Xt);
    // conv2: ybuf = conv(Xt, w2) + b2
    conv_kernel<ushort><<<cg, cbk, 0, stream>>>(Xt, Wtf + WSZ, b2, ybuf);
    // x2_max = max(ybuf, xmax);  Xt = pm(x2_max)
    maxt2_kernel<<<tg, tb, 0, stream>>>(ybuf, xmax, pa, Xt);
    // conv3 -> fp32 out
    conv_kernel<float><<<cg, cbk, 0, stream>>>(Xt, Wtf + 2 * WSZ, b3, (float*)d_out);
}